// Round 2
// baseline (1808.650 us; speedup 1.0000x reference)
//
#include <hip/hip_runtime.h>
#include <math.h>

#define D 64
#define EPS 1e-12f
#define LN_EPS 1e-5f

// ---------------------------------------------------------------------------
// Kernel A: per-node linears.
// thread-per-node: all lanes process the same (d,k) each step -> weight loads
// are wave-uniform (scalar-pipe broadcast); h/p rows live in registers with
// statically-indexed unrolled loops.
// __launch_bounds__(256, 1): we NEED ~170 VGPRs/thread to keep hx/px in
// registers (at the default budget the compiler allocated 84 and spilled
// both arrays -> 868 MB of scratch writes per dispatch, 1020us).
// ---------------------------------------------------------------------------
__global__ void __launch_bounds__(256, 1)
node_linears(const float* __restrict__ h, const float* __restrict__ p,
             const float* __restrict__ WK, const float* __restrict__ bK,
             const float* __restrict__ WV, const float* __restrict__ bV,
             const float* __restrict__ WB1, const float* __restrict__ bB1,
             const float* __restrict__ WB2, const float* __restrict__ bB2,
             const float* __restrict__ WC1, const float* __restrict__ bC1,
             const float* __restrict__ WC2, const float* __restrict__ bC2,
             float* __restrict__ sigmaQ, float* __restrict__ sigmaK,
             float* __restrict__ vhArr, float* __restrict__ B1h,
             float* __restrict__ B2h, float* __restrict__ C1p,
             float* __restrict__ C2p, int N)
{
    int n = blockIdx.x * blockDim.x + threadIdx.x;
    if (n >= N) return;

    float hx[D], px[D];
    const float4* h4 = (const float4*)(h + (size_t)n * D);
    const float4* p4 = (const float4*)(p + (size_t)n * D);
#pragma unroll
    for (int j = 0; j < D / 4; ++j) {
        float4 a = h4[j];
        hx[4*j+0] = a.x; hx[4*j+1] = a.y; hx[4*j+2] = a.z; hx[4*j+3] = a.w;
        float4 b = p4[j];
        px[4*j+0] = b.x; px[4*j+1] = b.y; px[4*j+2] = b.z; px[4*j+3] = b.w;
    }

    for (int d = 0; d < D; ++d) {
        // qk and vh: [2D] input = concat(h,p)
        float aq = bK[d];
        float av = bV[d];
        const float4* wk4 = (const float4*)(WK + (size_t)d * 2 * D);
        const float4* wv4 = (const float4*)(WV + (size_t)d * 2 * D);
#pragma unroll
        for (int j = 0; j < D / 4; ++j) {
            float4 wq = wk4[j];
            aq += wq.x*hx[4*j] + wq.y*hx[4*j+1] + wq.z*hx[4*j+2] + wq.w*hx[4*j+3];
            float4 wv = wv4[j];
            av += wv.x*hx[4*j] + wv.y*hx[4*j+1] + wv.z*hx[4*j+2] + wv.w*hx[4*j+3];
        }
#pragma unroll
        for (int j = 0; j < D / 4; ++j) {
            float4 wq = wk4[D/4 + j];
            aq += wq.x*px[4*j] + wq.y*px[4*j+1] + wq.z*px[4*j+2] + wq.w*px[4*j+3];
            float4 wv = wv4[D/4 + j];
            av += wv.x*px[4*j] + wv.y*px[4*j+1] + wv.z*px[4*j+2] + wv.w*px[4*j+3];
        }
        float a1 = bB1[d], a2 = bB2[d], c1 = bC1[d], c2 = bC2[d];
        const float4* w1 = (const float4*)(WB1 + (size_t)d * D);
        const float4* w2 = (const float4*)(WB2 + (size_t)d * D);
        const float4* u1 = (const float4*)(WC1 + (size_t)d * D);
        const float4* u2 = (const float4*)(WC2 + (size_t)d * D);
#pragma unroll
        for (int j = 0; j < D / 4; ++j) {
            float4 q1 = w1[j];
            a1 += q1.x*hx[4*j] + q1.y*hx[4*j+1] + q1.z*hx[4*j+2] + q1.w*hx[4*j+3];
            float4 q2 = w2[j];
            a2 += q2.x*hx[4*j] + q2.y*hx[4*j+1] + q2.z*hx[4*j+2] + q2.w*hx[4*j+3];
            float4 r1 = u1[j];
            c1 += r1.x*px[4*j] + r1.y*px[4*j+1] + r1.z*px[4*j+2] + r1.w*px[4*j+3];
            float4 r2 = u2[j];
            c2 += r2.x*px[4*j] + r2.y*px[4*j+1] + r2.z*px[4*j+2] + r2.w*px[4*j+3];
        }
        size_t o = (size_t)n * D + d;
        float sq = expf(tanhf(aq));
        float sk = expf(1.f / (1.f + expf(-aq)));
        sigmaQ[o] = sq;
        sigmaK[o] = sk;
        vhArr[o]  = av;
        B1h[o] = a1;
        B2h[o] = a2;
        C1p[o] = c1;
        C2p[o] = c2;
    }
}

// ---------------------------------------------------------------------------
// Kernel B: the edge pass. wave-per-edge, lane = feature dim.
//  - WB3 row `lane` preloaded into VGPRs (amortized over ~60 edges/wave)
//  - e-row loads are wave-uniform (single-line broadcast)
//  - hat_eta = B1h[src]+B2h[dst]+B3e; e_out = relu(hat_eta)
//  - alpha = <sigmaQ[src], sigmaK[dst]> via shfl_xor butterfly
//  - atomics accumulate the numerators; the 1/(S_sig+eps) factors out
//    of both segment sums, applied in finalize.
// ---------------------------------------------------------------------------
__global__ void __launch_bounds__(256)
edge_kernel(const float* __restrict__ e, const int* __restrict__ src,
            const int* __restrict__ dst,
            const float* __restrict__ WB3, const float* __restrict__ bB3,
            const float* __restrict__ B1h, const float* __restrict__ B2h,
            const float* __restrict__ sigmaQ, const float* __restrict__ sigmaK,
            const float* __restrict__ vhArr, const float* __restrict__ C2p,
            float* __restrict__ e_out, float* __restrict__ S_sig,
            float* __restrict__ S_v, float* __restrict__ S_p, int E)
{
    const int lane = threadIdx.x & 63;
    const int wid = __builtin_amdgcn_readfirstlane((int)(threadIdx.x >> 6));
    const int wpb = blockDim.x >> 6;
    const int gw = blockIdx.x * wpb + wid;
    const int nw = gridDim.x * wpb;

    // WB3 row for this lane, in registers (16 float4 = 64 VGPR)
    float4 wb3[16];
    const float4* w4 = (const float4*)(WB3 + (size_t)lane * D);
#pragma unroll
    for (int j = 0; j < 16; ++j) wb3[j] = w4[j];
    const float bb3 = bB3[lane];

    for (int ed = gw; ed < E; ed += nw) {
        int s = src[ed];   // wave-uniform
        int t = dst[ed];   // wave-uniform
        const float4* er4 = (const float4*)(e + (size_t)ed * D);  // uniform base
        float b3 = bb3;
#pragma unroll
        for (int j = 0; j < 16; ++j) {
            float4 ev = er4[j];  // broadcast
            b3 += ev.x*wb3[j].x + ev.y*wb3[j].y + ev.z*wb3[j].z + ev.w*wb3[j].w;
        }
        size_t so = (size_t)s * D + lane;
        size_t to = (size_t)t * D + lane;
        float he = B1h[so] + B2h[to] + b3;
        e_out[(size_t)ed * D + lane] = fmaxf(he, 0.f);
        float sg = 1.f / (1.f + expf(-he));

        float prod = sigmaQ[so] * sigmaK[to];
#pragma unroll
        for (int off = 32; off > 0; off >>= 1) prod += __shfl_xor(prod, off);
        // prod == alpha (same on all lanes)

        unsafeAtomicAdd(&S_sig[to], sg);
        unsafeAtomicAdd(&S_v[to], sg * prod * vhArr[so]);
        unsafeAtomicAdd(&S_p[to], sg * C2p[so]);
    }
}

// ---------------------------------------------------------------------------
// Kernel C: node finalize. wave-per-node, lane = feature dim.
// h_out buffer arrives holding S_v, p_out holding S_p.
// ---------------------------------------------------------------------------
__global__ void __launch_bounds__(256)
finalize(const float* __restrict__ vhArr, const float* __restrict__ C1p,
         const float* __restrict__ S_sig, const float* __restrict__ ln_g,
         const float* __restrict__ ln_b, float* __restrict__ h_out,
         float* __restrict__ p_out, int N)
{
    const int lane = threadIdx.x & 63;
    const int wid = threadIdx.x >> 6;
    const int wpb = blockDim.x >> 6;
    for (int n = blockIdx.x * wpb + wid; n < N; n += gridDim.x * wpb) {
        size_t o = (size_t)n * D + lane;
        float denom = S_sig[o] + EPS;
        float hv = vhArr[o] + h_out[o] / denom;
        hv = fmaxf(hv, 0.f);
        // LayerNorm across the 64 lanes
        float s = hv;
#pragma unroll
        for (int off = 32; off > 0; off >>= 1) s += __shfl_xor(s, off);
        float mu = s * (1.f / 64.f);
        float dv = hv - mu;
        float s2 = dv * dv;
#pragma unroll
        for (int off = 32; off > 0; off >>= 1) s2 += __shfl_xor(s2, off);
        float var = s2 * (1.f / 64.f);
        h_out[o] = dv * rsqrtf(var + LN_EPS) * ln_g[lane] + ln_b[lane];

        float pv = C1p[o] + p_out[o] / denom;
        p_out[o] = tanhf(pv);
    }
}

extern "C" void kernel_launch(void* const* d_in, const int* in_sizes, int n_in,
                              void* d_out, int out_size, void* d_ws, size_t ws_size,
                              hipStream_t stream) {
    const float* h    = (const float*)d_in[0];
    const float* e    = (const float*)d_in[1];
    const float* p    = (const float*)d_in[2];
    const float* WK   = (const float*)d_in[3];
    const float* bK   = (const float*)d_in[4];
    const float* WV   = (const float*)d_in[5];
    const float* bV   = (const float*)d_in[6];
    const float* WB1  = (const float*)d_in[7];
    const float* bB1  = (const float*)d_in[8];
    const float* WB2  = (const float*)d_in[9];
    const float* bB2  = (const float*)d_in[10];
    const float* WB3  = (const float*)d_in[11];
    const float* bB3  = (const float*)d_in[12];
    const float* WC1  = (const float*)d_in[13];
    const float* bC1  = (const float*)d_in[14];
    const float* WC2  = (const float*)d_in[15];
    const float* bC2  = (const float*)d_in[16];
    const float* ln_g = (const float*)d_in[17];
    const float* ln_b = (const float*)d_in[18];
    const int*   src  = (const int*)d_in[19];
    const int*   dst  = (const int*)d_in[20];

    const int N = in_sizes[0] / D;
    const int E = in_sizes[1] / D;
    const size_t ND = (size_t)N * D;

    float* out   = (float*)d_out;
    float* h_out = out;                       // accumulates S_v, then h_out
    float* e_out = out + ND;
    float* p_out = out + ND + (size_t)E * D;  // accumulates S_p, then p_out

    float* ws     = (float*)d_ws;             // needs 8*N*64*4 = 102.4 MB
    float* sigmaQ = ws + 0 * ND;
    float* sigmaK = ws + 1 * ND;
    float* vhArr  = ws + 2 * ND;
    float* B1h    = ws + 3 * ND;
    float* B2h    = ws + 4 * ND;
    float* C1p    = ws + 5 * ND;
    float* C2p    = ws + 6 * ND;
    float* S_sig  = ws + 7 * ND;

    hipMemsetAsync(h_out, 0, ND * sizeof(float), stream);
    hipMemsetAsync(p_out, 0, ND * sizeof(float), stream);
    hipMemsetAsync(S_sig, 0, ND * sizeof(float), stream);

    node_linears<<<(N + 255) / 256, 256, 0, stream>>>(
        h, p, WK, bK, WV, bV, WB1, bB1, WB2, bB2, WC1, bC1, WC2, bC2,
        sigmaQ, sigmaK, vhArr, B1h, B2h, C1p, C2p, N);

    edge_kernel<<<3200, 256, 0, stream>>>(
        e, src, dst, WB3, bB3, B1h, B2h, sigmaQ, sigmaK, vhArr, C2p,
        e_out, S_sig, h_out, p_out, E);

    finalize<<<512, 256, 0, stream>>>(
        vhArr, C1p, S_sig, ln_g, ln_b, h_out, p_out, N);
}

// Round 3
// 943.811 us; speedup vs baseline: 1.9163x; 1.9163x over previous
//
#include <hip/hip_runtime.h>
#include <math.h>

#define D 64
#define EPS 1e-12f
#define LN_EPS 1e-5f
#define NT 64   // nodes per block in node_linears

// ---------------------------------------------------------------------------
// Kernel A: per-node linears, tile-parallel.
// Block = 256 threads (4 waves) handles NT=64 nodes. x rows (h|p, 128 fp32)
// staged in LDS (32KB). Per matrix phase: weights staged swizzled in LDS
// (32KB), each lane copies ITS output-row d into VGPRs (<=128), then sweeps
// 16 nodes with wave-broadcast ds_read of x. All global writes are
// wave-coalesced 256B rows (n*64+lane) -- kills the R1 write amplification.
// __launch_bounds__(256,2): cap 256 VGPR so the 32-float4 weight row stays
// register-resident.
// ---------------------------------------------------------------------------
__global__ void __launch_bounds__(256, 2)
node_linears(const float* __restrict__ h, const float* __restrict__ p,
             const float* __restrict__ WK, const float* __restrict__ bK,
             const float* __restrict__ WV, const float* __restrict__ bV,
             const float* __restrict__ WB1, const float* __restrict__ bB1,
             const float* __restrict__ WB2, const float* __restrict__ bB2,
             const float* __restrict__ WC1, const float* __restrict__ bC1,
             const float* __restrict__ WC2, const float* __restrict__ bC2,
             float* __restrict__ sigmaQ, float* __restrict__ sigmaK,
             float* __restrict__ vhArr, float* __restrict__ B1h,
             float* __restrict__ B2h, float* __restrict__ C1p,
             float* __restrict__ C2p, int N)
{
    __shared__ float xs[NT * 128];    // [n][k], k<64 = h, k>=64 = p
    __shared__ float wsm[64 * 128];   // phase weight buffer, f4-swizzled

    const int t = threadIdx.x;
    const int lane = t & 63;
    const int wid = t >> 6;
    const int n0 = blockIdx.x * NT;

    float4* xs4 = (float4*)xs;
    float4* wsm4 = (float4*)wsm;

    // ---- stage x (coalesced) ----
    {
        const float4* h4 = (const float4*)h;
        const float4* p4 = (const float4*)p;
        for (int i = t; i < NT * 32; i += 256) {
            int n = i >> 5, kq = i & 31;
            int ng = n0 + n;
            float4 v = make_float4(0.f, 0.f, 0.f, 0.f);
            if (ng < N) v = (kq < 16) ? h4[(size_t)ng * 16 + kq]
                                      : p4[(size_t)ng * 16 + (kq - 16)];
            xs4[n * 32 + kq] = v;
        }
    }
    __syncthreads();

    // ================= phase helper: K=128 matrix =================
    // (written out twice: WK -> sigmaQ/sigmaK, WV -> vh)
#define STAGE_W128(W)                                                    \
    {                                                                    \
        const float4* w4 = (const float4*)(W);                           \
        for (int i = t; i < 64 * 32; i += 256) {                         \
            int d = i >> 5, j = i & 31;                                  \
            wsm4[d * 32 + (j ^ (d & 31))] = w4[i];                       \
        }                                                                \
    }                                                                    \
    __syncthreads();

#define LOAD_ROW128(wreg)                                                \
    _Pragma("unroll")                                                    \
    for (int j = 0; j < 32; ++j) wreg[j] = wsm4[lane * 32 + (j ^ (lane & 31))];

    // ---- WK phase ----
    {
        STAGE_W128(WK);
        float4 w[32];
        LOAD_ROW128(w);
        float bk = bK[lane];
#pragma unroll 1
        for (int i = 0; i < 16; ++i) {
            int n = wid * 16 + i;
            const float4* xv = (const float4*)&xs[n * 128];
            float a0 = 0.f, a1 = 0.f, a2 = 0.f, a3 = 0.f;
#pragma unroll
            for (int j = 0; j < 32; j += 4) {
                float4 x0 = xv[j + 0], x1 = xv[j + 1], x2 = xv[j + 2], x3 = xv[j + 3];
                a0 += w[j+0].x*x0.x + w[j+0].y*x0.y + w[j+0].z*x0.z + w[j+0].w*x0.w;
                a1 += w[j+1].x*x1.x + w[j+1].y*x1.y + w[j+1].z*x1.z + w[j+1].w*x1.w;
                a2 += w[j+2].x*x2.x + w[j+2].y*x2.y + w[j+2].z*x2.z + w[j+2].w*x2.w;
                a3 += w[j+3].x*x3.x + w[j+3].y*x3.y + w[j+3].z*x3.z + w[j+3].w*x3.w;
            }
            float aq = bk + (a0 + a1) + (a2 + a3);
            int ng = n0 + n;
            if (ng < N) {
                size_t o = (size_t)ng * 64 + lane;
                sigmaQ[o] = expf(tanhf(aq));
                sigmaK[o] = expf(1.f / (1.f + expf(-aq)));
            }
        }
        __syncthreads();
    }

    // ---- WV phase ----
    {
        STAGE_W128(WV);
        float4 w[32];
        LOAD_ROW128(w);
        float bv = bV[lane];
#pragma unroll 1
        for (int i = 0; i < 16; ++i) {
            int n = wid * 16 + i;
            const float4* xv = (const float4*)&xs[n * 128];
            float a0 = 0.f, a1 = 0.f, a2 = 0.f, a3 = 0.f;
#pragma unroll
            for (int j = 0; j < 32; j += 4) {
                float4 x0 = xv[j + 0], x1 = xv[j + 1], x2 = xv[j + 2], x3 = xv[j + 3];
                a0 += w[j+0].x*x0.x + w[j+0].y*x0.y + w[j+0].z*x0.z + w[j+0].w*x0.w;
                a1 += w[j+1].x*x1.x + w[j+1].y*x1.y + w[j+1].z*x1.z + w[j+1].w*x1.w;
                a2 += w[j+2].x*x2.x + w[j+2].y*x2.y + w[j+2].z*x2.z + w[j+2].w*x2.w;
                a3 += w[j+3].x*x3.x + w[j+3].y*x3.y + w[j+3].z*x3.z + w[j+3].w*x3.w;
            }
            float av = bv + (a0 + a1) + (a2 + a3);
            int ng = n0 + n;
            if (ng < N) vhArr[(size_t)ng * 64 + lane] = av;
        }
        __syncthreads();
    }

    // ================= dual K=64 phases =================
    // stage two 64x64 matrices at once (16KB each); x offset xoff (0 for h, 64 for p)
#define STAGE_W64x2(WA, WB)                                              \
    {                                                                    \
        for (int i = t; i < 2048; i += 256) {                            \
            int m = i >> 10;                                             \
            int r = i & 1023;                                            \
            int d = r >> 4, j = r & 15;                                  \
            const float4* w4 = m ? (const float4*)(WB) : (const float4*)(WA); \
            wsm4[m * 1024 + d * 16 + (j ^ (d & 15))] = w4[r];            \
        }                                                                \
    }                                                                    \
    __syncthreads();

    // ---- WB1/WB2 phase (input h) ----
    {
        STAGE_W64x2(WB1, WB2);
        float4 w1[16], w2[16];
#pragma unroll
        for (int j = 0; j < 16; ++j) {
            w1[j] = wsm4[lane * 16 + (j ^ (lane & 15))];
            w2[j] = wsm4[1024 + lane * 16 + (j ^ (lane & 15))];
        }
        float b1 = bB1[lane], b2 = bB2[lane];
#pragma unroll 1
        for (int i = 0; i < 16; ++i) {
            int n = wid * 16 + i;
            const float4* xv = (const float4*)&xs[n * 128];  // h part: f4 0..15
            float a0 = 0.f, a1 = 0.f, c0 = 0.f, c1 = 0.f;
#pragma unroll
            for (int j = 0; j < 16; j += 2) {
                float4 x0 = xv[j], x1 = xv[j + 1];
                a0 += w1[j].x*x0.x + w1[j].y*x0.y + w1[j].z*x0.z + w1[j].w*x0.w;
                a1 += w1[j+1].x*x1.x + w1[j+1].y*x1.y + w1[j+1].z*x1.z + w1[j+1].w*x1.w;
                c0 += w2[j].x*x0.x + w2[j].y*x0.y + w2[j].z*x0.z + w2[j].w*x0.w;
                c1 += w2[j+1].x*x1.x + w2[j+1].y*x1.y + w2[j+1].z*x1.z + w2[j+1].w*x1.w;
            }
            int ng = n0 + n;
            if (ng < N) {
                size_t o = (size_t)ng * 64 + lane;
                B1h[o] = b1 + a0 + a1;
                B2h[o] = b2 + c0 + c1;
            }
        }
        __syncthreads();
    }

    // ---- WC1/WC2 phase (input p) ----
    {
        STAGE_W64x2(WC1, WC2);
        float4 w1[16], w2[16];
#pragma unroll
        for (int j = 0; j < 16; ++j) {
            w1[j] = wsm4[lane * 16 + (j ^ (lane & 15))];
            w2[j] = wsm4[1024 + lane * 16 + (j ^ (lane & 15))];
        }
        float b1 = bC1[lane], b2 = bC2[lane];
#pragma unroll 1
        for (int i = 0; i < 16; ++i) {
            int n = wid * 16 + i;
            const float4* xv = (const float4*)&xs[n * 128 + 64];  // p part
            float a0 = 0.f, a1 = 0.f, c0 = 0.f, c1 = 0.f;
#pragma unroll
            for (int j = 0; j < 16; j += 2) {
                float4 x0 = xv[j], x1 = xv[j + 1];
                a0 += w1[j].x*x0.x + w1[j].y*x0.y + w1[j].z*x0.z + w1[j].w*x0.w;
                a1 += w1[j+1].x*x1.x + w1[j+1].y*x1.y + w1[j+1].z*x1.z + w1[j+1].w*x1.w;
                c0 += w2[j].x*x0.x + w2[j].y*x0.y + w2[j].z*x0.z + w2[j].w*x0.w;
                c1 += w2[j+1].x*x1.x + w2[j+1].y*x1.y + w2[j+1].z*x1.z + w2[j+1].w*x1.w;
            }
            int ng = n0 + n;
            if (ng < N) {
                size_t o = (size_t)ng * 64 + lane;
                C1p[o] = b1 + a0 + a1;
                C2p[o] = b2 + c0 + c1;
            }
        }
    }
}

// ---------------------------------------------------------------------------
// Kernel B: the edge pass. wave-per-edge, lane = feature dim.
// ---------------------------------------------------------------------------
__global__ void __launch_bounds__(256)
edge_kernel(const float* __restrict__ e, const int* __restrict__ src,
            const int* __restrict__ dst,
            const float* __restrict__ WB3, const float* __restrict__ bB3,
            const float* __restrict__ B1h, const float* __restrict__ B2h,
            const float* __restrict__ sigmaQ, const float* __restrict__ sigmaK,
            const float* __restrict__ vhArr, const float* __restrict__ C2p,
            float* __restrict__ e_out, float* __restrict__ S_sig,
            float* __restrict__ S_v, float* __restrict__ S_p, int E)
{
    const int lane = threadIdx.x & 63;
    const int wid = __builtin_amdgcn_readfirstlane((int)(threadIdx.x >> 6));
    const int wpb = blockDim.x >> 6;
    const int gw = blockIdx.x * wpb + wid;
    const int nw = gridDim.x * wpb;

    // WB3 row for this lane, in registers (16 float4 = 64 VGPR)
    float4 wb3[16];
    const float4* w4 = (const float4*)(WB3 + (size_t)lane * D);
#pragma unroll
    for (int j = 0; j < 16; ++j) wb3[j] = w4[j];
    const float bb3 = bB3[lane];

    for (int ed = gw; ed < E; ed += nw) {
        int s = src[ed];   // wave-uniform
        int t = dst[ed];   // wave-uniform
        const float4* er4 = (const float4*)(e + (size_t)ed * D);  // uniform base
        float b3 = bb3;
#pragma unroll
        for (int j = 0; j < 16; ++j) {
            float4 ev = er4[j];  // broadcast
            b3 += ev.x*wb3[j].x + ev.y*wb3[j].y + ev.z*wb3[j].z + ev.w*wb3[j].w;
        }
        size_t so = (size_t)s * D + lane;
        size_t to = (size_t)t * D + lane;
        float he = B1h[so] + B2h[to] + b3;
        e_out[(size_t)ed * D + lane] = fmaxf(he, 0.f);
        float sg = 1.f / (1.f + expf(-he));

        float prod = sigmaQ[so] * sigmaK[to];
#pragma unroll
        for (int off = 32; off > 0; off >>= 1) prod += __shfl_xor(prod, off);
        // prod == alpha (same on all lanes)

        unsafeAtomicAdd(&S_sig[to], sg);
        unsafeAtomicAdd(&S_v[to], sg * prod * vhArr[so]);
        unsafeAtomicAdd(&S_p[to], sg * C2p[so]);
    }
}

// ---------------------------------------------------------------------------
// Kernel C: node finalize. wave-per-node, lane = feature dim.
// h_out buffer arrives holding S_v, p_out holding S_p.
// ---------------------------------------------------------------------------
__global__ void __launch_bounds__(256)
finalize(const float* __restrict__ vhArr, const float* __restrict__ C1p,
         const float* __restrict__ S_sig, const float* __restrict__ ln_g,
         const float* __restrict__ ln_b, float* __restrict__ h_out,
         float* __restrict__ p_out, int N)
{
    const int lane = threadIdx.x & 63;
    const int wid = threadIdx.x >> 6;
    const int wpb = blockDim.x >> 6;
    for (int n = blockIdx.x * wpb + wid; n < N; n += gridDim.x * wpb) {
        size_t o = (size_t)n * D + lane;
        float denom = S_sig[o] + EPS;
        float hv = vhArr[o] + h_out[o] / denom;
        hv = fmaxf(hv, 0.f);
        float s = hv;
#pragma unroll
        for (int off = 32; off > 0; off >>= 1) s += __shfl_xor(s, off);
        float mu = s * (1.f / 64.f);
        float dv = hv - mu;
        float s2 = dv * dv;
#pragma unroll
        for (int off = 32; off > 0; off >>= 1) s2 += __shfl_xor(s2, off);
        float var = s2 * (1.f / 64.f);
        h_out[o] = dv * rsqrtf(var + LN_EPS) * ln_g[lane] + ln_b[lane];

        float pv = C1p[o] + p_out[o] / denom;
        p_out[o] = tanhf(pv);
    }
}

extern "C" void kernel_launch(void* const* d_in, const int* in_sizes, int n_in,
                              void* d_out, int out_size, void* d_ws, size_t ws_size,
                              hipStream_t stream) {
    const float* h    = (const float*)d_in[0];
    const float* e    = (const float*)d_in[1];
    const float* p    = (const float*)d_in[2];
    const float* WK   = (const float*)d_in[3];
    const float* bK   = (const float*)d_in[4];
    const float* WV   = (const float*)d_in[5];
    const float* bV   = (const float*)d_in[6];
    const float* WB1  = (const float*)d_in[7];
    const float* bB1  = (const float*)d_in[8];
    const float* WB2  = (const float*)d_in[9];
    const float* bB2  = (const float*)d_in[10];
    const float* WB3  = (const float*)d_in[11];
    const float* bB3  = (const float*)d_in[12];
    const float* WC1  = (const float*)d_in[13];
    const float* bC1  = (const float*)d_in[14];
    const float* WC2  = (const float*)d_in[15];
    const float* bC2  = (const float*)d_in[16];
    const float* ln_g = (const float*)d_in[17];
    const float* ln_b = (const float*)d_in[18];
    const int*   src  = (const int*)d_in[19];
    const int*   dst  = (const int*)d_in[20];

    const int N = in_sizes[0] / D;
    const int E = in_sizes[1] / D;
    const size_t ND = (size_t)N * D;

    float* out   = (float*)d_out;
    float* h_out = out;                       // accumulates S_v, then h_out
    float* e_out = out + ND;
    float* p_out = out + ND + (size_t)E * D;  // accumulates S_p, then p_out

    float* ws     = (float*)d_ws;             // needs 8*N*64*4 = 102.4 MB
    float* sigmaQ = ws + 0 * ND;
    float* sigmaK = ws + 1 * ND;
    float* vhArr  = ws + 2 * ND;
    float* B1h    = ws + 3 * ND;
    float* B2h    = ws + 4 * ND;
    float* C1p    = ws + 5 * ND;
    float* C2p    = ws + 6 * ND;
    float* S_sig  = ws + 7 * ND;

    hipMemsetAsync(h_out, 0, ND * sizeof(float), stream);
    hipMemsetAsync(p_out, 0, ND * sizeof(float), stream);
    hipMemsetAsync(S_sig, 0, ND * sizeof(float), stream);

    node_linears<<<(N + NT - 1) / NT, 256, 0, stream>>>(
        h, p, WK, bK, WV, bV, WB1, bB1, WB2, bB2, WC1, bC1, WC2, bC2,
        sigmaQ, sigmaK, vhArr, B1h, B2h, C1p, C2p, N);

    edge_kernel<<<3200, 256, 0, stream>>>(
        e, src, dst, WB3, bB3, B1h, B2h, sigmaQ, sigmaK, vhArr, C2p,
        e_out, S_sig, h_out, p_out, E);

    finalize<<<512, 256, 0, stream>>>(
        vhArr, C1p, S_sig, ln_g, ln_b, h_out, p_out, N);
}

// Round 4
// 929.060 us; speedup vs baseline: 1.9468x; 1.0159x over previous
//
#include <hip/hip_runtime.h>
#include <math.h>

#define D 64
#define EPS 1e-12f
#define LN_EPS 1e-5f
#define NT 64   // nodes per block in node_linears

// ---------------------------------------------------------------------------
// Kernel A: per-node linears, tile-parallel (unchanged from R3 -- verified).
// ---------------------------------------------------------------------------
__global__ void __launch_bounds__(256, 2)
node_linears(const float* __restrict__ h, const float* __restrict__ p,
             const float* __restrict__ WK, const float* __restrict__ bK,
             const float* __restrict__ WV, const float* __restrict__ bV,
             const float* __restrict__ WB1, const float* __restrict__ bB1,
             const float* __restrict__ WB2, const float* __restrict__ bB2,
             const float* __restrict__ WC1, const float* __restrict__ bC1,
             const float* __restrict__ WC2, const float* __restrict__ bC2,
             float* __restrict__ sigmaQ, float* __restrict__ sigmaK,
             float* __restrict__ vhArr, float* __restrict__ B1h,
             float* __restrict__ B2h, float* __restrict__ C1p,
             float* __restrict__ C2p, int N)
{
    __shared__ float xs[NT * 128];    // [n][k], k<64 = h, k>=64 = p
    __shared__ float wsm[64 * 128];   // phase weight buffer, f4-swizzled

    const int t = threadIdx.x;
    const int lane = t & 63;
    const int wid = t >> 6;
    const int n0 = blockIdx.x * NT;

    float4* xs4 = (float4*)xs;
    float4* wsm4 = (float4*)wsm;

    {
        const float4* h4 = (const float4*)h;
        const float4* p4 = (const float4*)p;
        for (int i = t; i < NT * 32; i += 256) {
            int n = i >> 5, kq = i & 31;
            int ng = n0 + n;
            float4 v = make_float4(0.f, 0.f, 0.f, 0.f);
            if (ng < N) v = (kq < 16) ? h4[(size_t)ng * 16 + kq]
                                      : p4[(size_t)ng * 16 + (kq - 16)];
            xs4[n * 32 + kq] = v;
        }
    }
    __syncthreads();

#define STAGE_W128(W)                                                    \
    {                                                                    \
        const float4* w4 = (const float4*)(W);                           \
        for (int i = t; i < 64 * 32; i += 256) {                         \
            int d = i >> 5, j = i & 31;                                  \
            wsm4[d * 32 + (j ^ (d & 31))] = w4[i];                       \
        }                                                                \
    }                                                                    \
    __syncthreads();

#define LOAD_ROW128(wreg)                                                \
    _Pragma("unroll")                                                    \
    for (int j = 0; j < 32; ++j) wreg[j] = wsm4[lane * 32 + (j ^ (lane & 31))];

    // ---- WK phase ----
    {
        STAGE_W128(WK);
        float4 w[32];
        LOAD_ROW128(w);
        float bk = bK[lane];
#pragma unroll 1
        for (int i = 0; i < 16; ++i) {
            int n = wid * 16 + i;
            const float4* xv = (const float4*)&xs[n * 128];
            float a0 = 0.f, a1 = 0.f, a2 = 0.f, a3 = 0.f;
#pragma unroll
            for (int j = 0; j < 32; j += 4) {
                float4 x0 = xv[j + 0], x1 = xv[j + 1], x2 = xv[j + 2], x3 = xv[j + 3];
                a0 += w[j+0].x*x0.x + w[j+0].y*x0.y + w[j+0].z*x0.z + w[j+0].w*x0.w;
                a1 += w[j+1].x*x1.x + w[j+1].y*x1.y + w[j+1].z*x1.z + w[j+1].w*x1.w;
                a2 += w[j+2].x*x2.x + w[j+2].y*x2.y + w[j+2].z*x2.z + w[j+2].w*x2.w;
                a3 += w[j+3].x*x3.x + w[j+3].y*x3.y + w[j+3].z*x3.z + w[j+3].w*x3.w;
            }
            float aq = bk + (a0 + a1) + (a2 + a3);
            int ng = n0 + n;
            if (ng < N) {
                size_t o = (size_t)ng * 64 + lane;
                sigmaQ[o] = expf(tanhf(aq));
                sigmaK[o] = expf(1.f / (1.f + expf(-aq)));
            }
        }
        __syncthreads();
    }

    // ---- WV phase ----
    {
        STAGE_W128(WV);
        float4 w[32];
        LOAD_ROW128(w);
        float bv = bV[lane];
#pragma unroll 1
        for (int i = 0; i < 16; ++i) {
            int n = wid * 16 + i;
            const float4* xv = (const float4*)&xs[n * 128];
            float a0 = 0.f, a1 = 0.f, a2 = 0.f, a3 = 0.f;
#pragma unroll
            for (int j = 0; j < 32; j += 4) {
                float4 x0 = xv[j + 0], x1 = xv[j + 1], x2 = xv[j + 2], x3 = xv[j + 3];
                a0 += w[j+0].x*x0.x + w[j+0].y*x0.y + w[j+0].z*x0.z + w[j+0].w*x0.w;
                a1 += w[j+1].x*x1.x + w[j+1].y*x1.y + w[j+1].z*x1.z + w[j+1].w*x1.w;
                a2 += w[j+2].x*x2.x + w[j+2].y*x2.y + w[j+2].z*x2.z + w[j+2].w*x2.w;
                a3 += w[j+3].x*x3.x + w[j+3].y*x3.y + w[j+3].z*x3.z + w[j+3].w*x3.w;
            }
            float av = bv + (a0 + a1) + (a2 + a3);
            int ng = n0 + n;
            if (ng < N) vhArr[(size_t)ng * 64 + lane] = av;
        }
        __syncthreads();
    }

#define STAGE_W64x2(WA, WB)                                              \
    {                                                                    \
        for (int i = t; i < 2048; i += 256) {                            \
            int m = i >> 10;                                             \
            int r = i & 1023;                                            \
            int d = r >> 4, j = r & 15;                                  \
            const float4* w4 = m ? (const float4*)(WB) : (const float4*)(WA); \
            wsm4[m * 1024 + d * 16 + (j ^ (d & 15))] = w4[r];            \
        }                                                                \
    }                                                                    \
    __syncthreads();

    // ---- WB1/WB2 phase (input h) ----
    {
        STAGE_W64x2(WB1, WB2);
        float4 w1[16], w2[16];
#pragma unroll
        for (int j = 0; j < 16; ++j) {
            w1[j] = wsm4[lane * 16 + (j ^ (lane & 15))];
            w2[j] = wsm4[1024 + lane * 16 + (j ^ (lane & 15))];
        }
        float b1 = bB1[lane], b2 = bB2[lane];
#pragma unroll 1
        for (int i = 0; i < 16; ++i) {
            int n = wid * 16 + i;
            const float4* xv = (const float4*)&xs[n * 128];
            float a0 = 0.f, a1 = 0.f, c0 = 0.f, c1 = 0.f;
#pragma unroll
            for (int j = 0; j < 16; j += 2) {
                float4 x0 = xv[j], x1 = xv[j + 1];
                a0 += w1[j].x*x0.x + w1[j].y*x0.y + w1[j].z*x0.z + w1[j].w*x0.w;
                a1 += w1[j+1].x*x1.x + w1[j+1].y*x1.y + w1[j+1].z*x1.z + w1[j+1].w*x1.w;
                c0 += w2[j].x*x0.x + w2[j].y*x0.y + w2[j].z*x0.z + w2[j].w*x0.w;
                c1 += w2[j+1].x*x1.x + w2[j+1].y*x1.y + w2[j+1].z*x1.z + w2[j+1].w*x1.w;
            }
            int ng = n0 + n;
            if (ng < N) {
                size_t o = (size_t)ng * 64 + lane;
                B1h[o] = b1 + a0 + a1;
                B2h[o] = b2 + c0 + c1;
            }
        }
        __syncthreads();
    }

    // ---- WC1/WC2 phase (input p) ----
    {
        STAGE_W64x2(WC1, WC2);
        float4 w1[16], w2[16];
#pragma unroll
        for (int j = 0; j < 16; ++j) {
            w1[j] = wsm4[lane * 16 + (j ^ (lane & 15))];
            w2[j] = wsm4[1024 + lane * 16 + (j ^ (lane & 15))];
        }
        float b1 = bC1[lane], b2 = bC2[lane];
#pragma unroll 1
        for (int i = 0; i < 16; ++i) {
            int n = wid * 16 + i;
            const float4* xv = (const float4*)&xs[n * 128 + 64];
            float a0 = 0.f, a1 = 0.f, c0 = 0.f, c1 = 0.f;
#pragma unroll
            for (int j = 0; j < 16; j += 2) {
                float4 x0 = xv[j], x1 = xv[j + 1];
                a0 += w1[j].x*x0.x + w1[j].y*x0.y + w1[j].z*x0.z + w1[j].w*x0.w;
                a1 += w1[j+1].x*x1.x + w1[j+1].y*x1.y + w1[j+1].z*x1.z + w1[j+1].w*x1.w;
                c0 += w2[j].x*x0.x + w2[j].y*x0.y + w2[j].z*x0.z + w2[j].w*x0.w;
                c1 += w2[j+1].x*x1.x + w2[j+1].y*x1.y + w2[j+1].z*x1.z + w2[j+1].w*x1.w;
            }
            int ng = n0 + n;
            if (ng < N) {
                size_t o = (size_t)ng * 64 + lane;
                C1p[o] = b1 + a0 + a1;
                C2p[o] = b2 + c0 + c1;
            }
        }
    }
}

// ---------------------------------------------------------------------------
// dst-bucketing pipeline: hist -> chunk sums -> scan chunks -> offsets ->
// scatter. Only int atomics (1.6M total), no fp32 atomics anywhere.
// ---------------------------------------------------------------------------
__global__ void hist_kernel(const int* __restrict__ dst, int* __restrict__ cnt, int E) {
    int i = blockIdx.x * blockDim.x + threadIdx.x;
    if (i < E) atomicAdd(&cnt[dst[i]], 1);
}

__global__ void chunksum_kernel(const int* __restrict__ cnt, int* __restrict__ csum, int N) {
    __shared__ int sc[256];
    int t = threadIdx.x;
    int i = blockIdx.x * 256 + t;
    sc[t] = (i < N) ? cnt[i] : 0;
    __syncthreads();
    for (int off = 128; off > 0; off >>= 1) {
        if (t < off) sc[t] += sc[t + off];
        __syncthreads();
    }
    if (t == 0) csum[blockIdx.x] = sc[0];
}

// single block; nch <= 256 (N=50000 -> 196 chunks)
__global__ void scanchunk_kernel(int* __restrict__ csum, int nch) {
    __shared__ int sc[256];
    int t = threadIdx.x;
    int v = (t < nch) ? csum[t] : 0;
    sc[t] = v;
    __syncthreads();
    for (int off = 1; off < 256; off <<= 1) {
        int y = (t >= off) ? sc[t - off] : 0;
        __syncthreads();
        sc[t] += y;
        __syncthreads();
    }
    if (t < nch) csum[t] = sc[t] - v;   // exclusive prefix
}

__global__ void offsets_kernel(const int* __restrict__ cnt, const int* __restrict__ csum,
                               int* __restrict__ offs, int N) {
    __shared__ int sc[256];
    int t = threadIdx.x;
    int i = blockIdx.x * 256 + t;
    int v = (i < N) ? cnt[i] : 0;
    sc[t] = v;
    __syncthreads();
    for (int off = 1; off < 256; off <<= 1) {
        int y = (t >= off) ? sc[t - off] : 0;
        __syncthreads();
        sc[t] += y;
        __syncthreads();
    }
    if (i < N) offs[i] = csum[blockIdx.x] + sc[t] - v;  // global exclusive prefix
}

// consumes offs: afterwards offs[n] == end of bucket n (start = end - cnt[n])
__global__ void scatter_kernel(const int* __restrict__ dst, int* __restrict__ offs,
                               int* __restrict__ bucket, int E) {
    int i = blockIdx.x * blockDim.x + threadIdx.x;
    if (i < E) {
        int pos = atomicAdd(&offs[dst[i]], 1);
        bucket[pos] = i;
    }
}

// ---------------------------------------------------------------------------
// Kernel B: edge compute. wave-per-edge, lane = feature dim. NO atomics.
// Writes pre-activation he into the e_out region and alpha[E].
// ---------------------------------------------------------------------------
__global__ void __launch_bounds__(256)
edge_compute(const float* __restrict__ e, const int* __restrict__ src,
             const int* __restrict__ dst,
             const float* __restrict__ WB3, const float* __restrict__ bB3,
             const float* __restrict__ B1h, const float* __restrict__ B2h,
             const float* __restrict__ sigmaQ, const float* __restrict__ sigmaK,
             float* __restrict__ he_out, float* __restrict__ alpha, int E)
{
    const int lane = threadIdx.x & 63;
    const int wid = __builtin_amdgcn_readfirstlane((int)(threadIdx.x >> 6));
    const int wpb = blockDim.x >> 6;
    const int gw = blockIdx.x * wpb + wid;
    const int nw = gridDim.x * wpb;

    float4 wb3[16];
    const float4* w4 = (const float4*)(WB3 + (size_t)lane * D);
#pragma unroll
    for (int j = 0; j < 16; ++j) wb3[j] = w4[j];
    const float bb3 = bB3[lane];

    for (int ed = gw; ed < E; ed += nw) {
        int s = src[ed];   // wave-uniform
        int t = dst[ed];   // wave-uniform
        const float4* er4 = (const float4*)(e + (size_t)ed * D);
        float b3 = bb3;
#pragma unroll
        for (int j = 0; j < 16; ++j) {
            float4 ev = er4[j];
            b3 += ev.x*wb3[j].x + ev.y*wb3[j].y + ev.z*wb3[j].z + ev.w*wb3[j].w;
        }
        size_t so = (size_t)s * D + lane;
        size_t to = (size_t)t * D + lane;
        float he = B1h[so] + B2h[to] + b3;
        he_out[(size_t)ed * D + lane] = he;

        float prod = sigmaQ[so] * sigmaK[to];
#pragma unroll
        for (int off = 32; off > 0; off >>= 1) prod += __shfl_xor(prod, off);
        if (lane == 0) alpha[ed] = prod;
    }
}

// ---------------------------------------------------------------------------
// Kernel C: gather + finalize. wave-per-node, lane = feature dim.
// Walks the node's dst-bucket: reads he rows (each edge row exactly once),
// recomputes sigmoid in-register, accumulates S_sig/S_v/S_p in 3 VGPRs,
// overwrites the he row with relu(he) (producing e_out in place), then does
// the h/p epilogue (denominator, relu, LayerNorm, tanh) fused.
// ---------------------------------------------------------------------------
__global__ void __launch_bounds__(256)
gather_finalize(const int* __restrict__ bucket, const int* __restrict__ offs_end,
                const int* __restrict__ cnt, const int* __restrict__ src,
                const float* __restrict__ alpha, const float* __restrict__ vhArr,
                const float* __restrict__ C1p, const float* __restrict__ C2p,
                const float* __restrict__ ln_g, const float* __restrict__ ln_b,
                float* __restrict__ he_eout, float* __restrict__ h_out,
                float* __restrict__ p_out, int N)
{
    const int lane = threadIdx.x & 63;
    const int wid = threadIdx.x >> 6;
    const int wpb = blockDim.x >> 6;
    const float lg = ln_g[lane], lb = ln_b[lane];

    for (int n = blockIdx.x * wpb + wid; n < N; n += gridDim.x * wpb) {
        const int end = offs_end[n];
        const int deg = cnt[n];
        const int start = end - deg;

        float asig = 0.f, av = 0.f, ap = 0.f;
        int eid = (deg > 0) ? bucket[start] : 0;
        for (int k = start; k < end; ++k) {
            int eidn = (k + 1 < end) ? bucket[k + 1] : 0;   // prefetch next id
            int s = src[eid];
            float al = alpha[eid];
            size_t eo = (size_t)eid * D + lane;
            float he = he_eout[eo];
            size_t so = (size_t)s * D + lane;
            float vhs = vhArr[so];
            float c2s = C2p[so];
            he_eout[eo] = fmaxf(he, 0.f);                   // e_out in place
            float sg = 1.f / (1.f + expf(-he));
            asig += sg;
            av += sg * al * vhs;
            ap += sg * c2s;
            eid = eidn;
        }

        size_t o = (size_t)n * D + lane;
        float denom = asig + EPS;
        float hv = vhArr[o] + av / denom;
        hv = fmaxf(hv, 0.f);
        float s = hv;
#pragma unroll
        for (int off = 32; off > 0; off >>= 1) s += __shfl_xor(s, off);
        float mu = s * (1.f / 64.f);
        float dv = hv - mu;
        float s2 = dv * dv;
#pragma unroll
        for (int off = 32; off > 0; off >>= 1) s2 += __shfl_xor(s2, off);
        float var = s2 * (1.f / 64.f);
        h_out[o] = dv * rsqrtf(var + LN_EPS) * lg + lb;

        float pv = C1p[o] + ap / denom;
        p_out[o] = tanhf(pv);
    }
}

extern "C" void kernel_launch(void* const* d_in, const int* in_sizes, int n_in,
                              void* d_out, int out_size, void* d_ws, size_t ws_size,
                              hipStream_t stream) {
    const float* h    = (const float*)d_in[0];
    const float* e    = (const float*)d_in[1];
    const float* p    = (const float*)d_in[2];
    const float* WK   = (const float*)d_in[3];
    const float* bK   = (const float*)d_in[4];
    const float* WV   = (const float*)d_in[5];
    const float* bV   = (const float*)d_in[6];
    const float* WB1  = (const float*)d_in[7];
    const float* bB1  = (const float*)d_in[8];
    const float* WB2  = (const float*)d_in[9];
    const float* bB2  = (const float*)d_in[10];
    const float* WB3  = (const float*)d_in[11];
    const float* bB3  = (const float*)d_in[12];
    const float* WC1  = (const float*)d_in[13];
    const float* bC1  = (const float*)d_in[14];
    const float* WC2  = (const float*)d_in[15];
    const float* bC2  = (const float*)d_in[16];
    const float* ln_g = (const float*)d_in[17];
    const float* ln_b = (const float*)d_in[18];
    const int*   src  = (const int*)d_in[19];
    const int*   dst  = (const int*)d_in[20];

    const int N = in_sizes[0] / D;
    const int E = in_sizes[1] / D;
    const size_t ND = (size_t)N * D;

    float* out   = (float*)d_out;
    float* h_out = out;
    float* e_out = out + ND;                  // holds he, then relu(he)
    float* p_out = out + ND + (size_t)E * D;

    // ws layout: 7*ND + E floats + (2N + E) ints  ~= 96.6 MB
    float* ws     = (float*)d_ws;
    float* sigmaQ = ws + 0 * ND;
    float* sigmaK = ws + 1 * ND;
    float* vhArr  = ws + 2 * ND;
    float* B1h    = ws + 3 * ND;
    float* B2h    = ws + 4 * ND;
    float* C1p    = ws + 5 * ND;
    float* C2p    = ws + 6 * ND;
    float* alpha  = ws + 7 * ND;              // E floats
    int*   cnt    = (int*)(ws + 7 * ND + E);  // N ints
    int*   offs   = cnt + N;                  // N ints
    int*   bucket = offs + N;                 // E ints
    int*   csum   = bucket + E;               // nchunk ints (<=256)

    const int nchunk = (N + 255) / 256;

    hipMemsetAsync(cnt, 0, (size_t)N * sizeof(int), stream);

    node_linears<<<(N + NT - 1) / NT, 256, 0, stream>>>(
        h, p, WK, bK, WV, bV, WB1, bB1, WB2, bB2, WC1, bC1, WC2, bC2,
        sigmaQ, sigmaK, vhArr, B1h, B2h, C1p, C2p, N);

    hist_kernel<<<(E + 255) / 256, 256, 0, stream>>>(dst, cnt, E);
    chunksum_kernel<<<nchunk, 256, 0, stream>>>(cnt, csum, N);
    scanchunk_kernel<<<1, 256, 0, stream>>>(csum, nchunk);
    offsets_kernel<<<nchunk, 256, 0, stream>>>(cnt, csum, offs, N);
    scatter_kernel<<<(E + 255) / 256, 256, 0, stream>>>(dst, offs, bucket, E);

    edge_compute<<<3200, 256, 0, stream>>>(
        e, src, dst, WB3, bB3, B1h, B2h, sigmaQ, sigmaK, e_out, alpha, E);

    gather_finalize<<<(N + 3) / 4, 256, 0, stream>>>(
        bucket, offs, cnt, src, alpha, vhArr, C1p, C2p, ln_g, ln_b,
        e_out, h_out, p_out, N);
}